// Round 1
// baseline (3929.338 us; speedup 1.0000x reference)
//
#include <hip/hip_runtime.h>
#include <math.h>

// Problem constants
// B=16384, IN=128, H=512, Y=32, K=8
// out = sqrtm(Sigma_inv + 1e-6 I) per batch, [16384,32,32] fp32

// ---------------------------------------------------------------------------
// Generic tiled fp32 GEMM: C[M,N] = act(A[M,K] @ B[K,N] + bias)
// ACT: 0=none, 1=relu, 2=softplus -> store 1/(D*D) with D = softplus(z)+1e-3
// BM=BN=64, BK=16, 256 threads, 4x4 micro-tile per thread.
// M is always a multiple of 64 here; N may be smaller than 64 (N=32 case).
// ---------------------------------------------------------------------------
template <int ACT>
__global__ __launch_bounds__(256) void gemm_act(const float* __restrict__ A,
                                                const float* __restrict__ Bm,
                                                const float* __restrict__ bias,
                                                float* __restrict__ C,
                                                int M, int N, int K) {
  __shared__ float As[16][68];  // [k][m], padded
  __shared__ float Bs[16][68];  // [k][n], padded (68*4 bytes keeps 16B align)
  const int tid = threadIdx.x;
  const int bm = blockIdx.y * 64;
  const int bn = blockIdx.x * 64;
  const int tx = tid & 15, ty = tid >> 4;
  const int arow = tid >> 2, acol4 = (tid & 3) << 2;
  const int brow = tid >> 4, bcol4 = (tid & 15) << 2;
  float acc[4][4] = {};

  for (int k0 = 0; k0 < K; k0 += 16) {
    float4 av = *(const float4*)(A + (size_t)(bm + arow) * K + (k0 + acol4));
    As[acol4 + 0][arow] = av.x;
    As[acol4 + 1][arow] = av.y;
    As[acol4 + 2][arow] = av.z;
    As[acol4 + 3][arow] = av.w;
    float4 bv = make_float4(0.f, 0.f, 0.f, 0.f);
    if (bn + bcol4 < N)
      bv = *(const float4*)(Bm + (size_t)(k0 + brow) * N + (bn + bcol4));
    *(float4*)&Bs[brow][bcol4] = bv;
    __syncthreads();
#pragma unroll
    for (int k = 0; k < 16; ++k) {
      float ar[4], br[4];
#pragma unroll
      for (int i = 0; i < 4; ++i) ar[i] = As[k][(ty << 2) + i];
#pragma unroll
      for (int j = 0; j < 4; ++j) br[j] = Bs[k][(tx << 2) + j];
#pragma unroll
      for (int i = 0; i < 4; ++i)
#pragma unroll
        for (int j = 0; j < 4; ++j) acc[i][j] = fmaf(ar[i], br[j], acc[i][j]);
    }
    __syncthreads();
  }

#pragma unroll
  for (int i = 0; i < 4; ++i) {
    int row = bm + (ty << 2) + i;
#pragma unroll
    for (int j = 0; j < 4; ++j) {
      int col = bn + (tx << 2) + j;
      if (col < N) {
        float v = acc[i][j] + bias[col];
        if (ACT == 1) v = fmaxf(v, 0.f);
        if (ACT == 2) {
          // softplus (stable, matches logaddexp(z,0)) then 1/(D*D)
          float sp = fmaxf(v, 0.f) + log1pf(expf(-fabsf(v)));
          float D = sp + 1e-3f;
          v = 1.f / (D * D);
        }
        C[(size_t)row * N + col] = v;
      }
    }
  }
}

// ---------------------------------------------------------------------------
// Per-batch: Woodbury assembly (double precision for the ill-conditioned
// capacitance solve) + 32x32 symmetric Jacobi eigh (fp32, parallel-ordered
// round-robin, 8 sweeps) + Q sqrt(Lambda) Q^T output.
// One wave (64 threads) per batch element.
// ---------------------------------------------------------------------------
__global__ __launch_bounds__(64) void woodbury_sqrtm(
    const float* __restrict__ invD2g, const float* __restrict__ Vg,
    float* __restrict__ out) {
  const int b = blockIdx.x;
  const int lane = threadIdx.x;

  __shared__ float Am[32][33];  // +1 pad: column access banks (i+p)%32, conflict-free
  __shared__ float Qm[32][33];
  __shared__ float a_d[32];
  __shared__ float Vb[32][8];
  __shared__ float Wb[32][8];
  __shared__ double Md[8][9];
  __shared__ double Ld[8][9];
  __shared__ double Ud[32][8];
  __shared__ float rc[16], rs[16];
  __shared__ int rp[16], rq[16];
  __shared__ float sv[32];

  // Load invD2 row [32] and V row [32][8]
  if (lane < 32) a_d[lane] = invD2g[(size_t)b * 32 + lane];
  {
    float4 v = ((const float4*)(Vg + (size_t)b * 256))[lane];
    ((float4*)&Vb[0][0])[lane] = v;
  }
  __syncthreads();

  // W = V * invD2 (per row y)
  {
    int y = lane >> 1, h = lane & 1;
    float d = a_d[y];
#pragma unroll
    for (int k = 0; k < 4; ++k) {
      int kk = (h << 2) + k;
      Wb[y][kk] = Vb[y][kk] * d;
    }
  }
  __syncthreads();

  // M = I + V^T W  (8x8, each lane one entry, double accumulate)
  {
    int i = lane >> 3, j = lane & 7;
    double acc = (i == j) ? 1.0 : 0.0;
#pragma unroll
    for (int y = 0; y < 32; ++y) acc += (double)Vb[y][i] * (double)Wb[y][j];
    Md[i][j] = acc;
  }
  __syncthreads();

  // Cholesky M = L L^T (8x8, serial on lane 0, double)
  if (lane == 0) {
    for (int k = 0; k < 8; ++k) {
      double d = Md[k][k];
      for (int i = 0; i < k; ++i) d -= Ld[k][i] * Ld[k][i];
      double lkk = sqrt(fmax(d, 1e-30));
      Ld[k][k] = lkk;
      double inv = 1.0 / lkk;
      for (int r = k + 1; r < 8; ++r) {
        double v = Md[r][k];
        for (int i = 0; i < k; ++i) v -= Ld[r][i] * Ld[k][i];
        Ld[r][k] = v * inv;
      }
    }
  }
  __syncthreads();

  // U = W L^{-T}  (solve U L^T = W, forward in j; lanes 0..31 = rows)
  if (lane < 32) {
    double u[8];
#pragma unroll
    for (int j = 0; j < 8; ++j) {
      double v = (double)Wb[lane][j];
      for (int i = 0; i < j; ++i) v -= u[i] * Ld[j][i];
      u[j] = v / Ld[j][j];
      Ud[lane][j] = u[j];
    }
  }
  __syncthreads();

  // A = diag(invD2 + eps) - U U^T ; Q = I
#pragma unroll
  for (int it = 0; it < 16; ++it) {
    int id = lane + (it << 6);
    int i = id >> 5, j = id & 31;
    double acc = 0.0;
#pragma unroll
    for (int k = 0; k < 8; ++k) acc += Ud[i][k] * Ud[j][k];
    double v = -acc;
    if (i == j) v += (double)a_d[i] + 1e-6;  // fold in sqrt(eig + EPS)
    Am[i][j] = (float)v;
    Qm[i][j] = (i == j) ? 1.f : 0.f;
  }
  __syncthreads();

  // Jacobi: 8 sweeps x 31 rounds; round-robin pairing covers all C(32,2) pairs
  for (int sweep = 0; sweep < 8; ++sweep) {
    for (int r = 0; r < 31; ++r) {
      // Phase 1: 16 lanes compute rotation params for 16 disjoint pairs
      if (lane < 16) {
        int istar = (r << 4) % 31;  // 16 = inverse of 2 mod 31
        int p, q;
        if (lane == 0) {
          p = istar;
          q = 31;
        } else {
          int i1 = istar + lane;
          if (i1 >= 31) i1 -= 31;
          int j1 = istar - lane;
          if (j1 < 0) j1 += 31;
          p = i1 < j1 ? i1 : j1;
          q = i1 < j1 ? j1 : i1;
        }
        float app = Am[p][p], aqq = Am[q][q], apq = Am[p][q];
        float c = 1.f, s = 0.f;
        if (fabsf(apq) > 1e-36f) {
          float tau = (aqq - app) / (2.f * apq);
          float t = 1.f / (fabsf(tau) + sqrtf(1.f + tau * tau));
          t = (tau >= 0.f) ? t : -t;
          c = 1.f / sqrtf(1.f + t * t);
          s = t * c;
        }
        rp[lane] = p;
        rq[lane] = q;
        rc[lane] = c;
        rs[lane] = s;
      }
      __syncthreads();
      // Phase 2: row update  B = J^T A   (rows p,q of each pair, all cols)
#pragma unroll
      for (int it = 0; it < 8; ++it) {
        int id = lane + (it << 6);
        int tp = id >> 5, j = id & 31;
        int p = rp[tp], q = rq[tp];
        float c = rc[tp], s = rs[tp];
        float ap = Am[p][j], aq = Am[q][j];
        Am[p][j] = c * ap - s * aq;
        Am[q][j] = s * ap + c * aq;
      }
      __syncthreads();
      // Phase 3: col update  A = B J, and accumulate Q = Q J
#pragma unroll
      for (int it = 0; it < 8; ++it) {
        int id = lane + (it << 6);
        int tp = id >> 5, i = id & 31;
        int p = rp[tp], q = rq[tp];
        float c = rc[tp], s = rs[tp];
        float ap = Am[i][p], aq = Am[i][q];
        Am[i][p] = c * ap - s * aq;
        Am[i][q] = s * ap + c * aq;
        float qp = Qm[i][p], qq = Qm[i][q];
        Qm[i][p] = c * qp - s * qq;
        Qm[i][q] = s * qp + c * qq;
      }
      __syncthreads();
    }
  }

  // s = sqrt(eigvals) (EPS already folded into A's diagonal)
  if (lane < 32) sv[lane] = sqrtf(fmaxf(Am[lane][lane], 0.f));
  __syncthreads();

  // R = Q diag(s)  (stored into Am)
#pragma unroll
  for (int it = 0; it < 16; ++it) {
    int id = lane + (it << 6);
    int i = id >> 5, k = id & 31;
    Am[i][k] = Qm[i][k] * sv[k];
  }
  __syncthreads();

  // out = Q R^T  (coalesced: consecutive lanes -> consecutive j)
  float* ob = out + (size_t)b * 1024;
  for (int it = 0; it < 16; ++it) {
    int id = lane + (it << 6);
    int i = id >> 5, j = id & 31;
    float acc = 0.f;
#pragma unroll
    for (int k = 0; k < 32; ++k) acc = fmaf(Qm[i][k], Am[j][k], acc);
    ob[(i << 5) + j] = acc;
  }
}

// ---------------------------------------------------------------------------
extern "C" void kernel_launch(void* const* d_in, const int* in_sizes, int n_in,
                              void* d_out, int out_size, void* d_ws,
                              size_t ws_size, hipStream_t stream) {
  const float* x = (const float*)d_in[0];
  const float* W1 = (const float*)d_in[1];
  const float* b1 = (const float*)d_in[2];
  const float* WD = (const float*)d_in[3];
  const float* bD = (const float*)d_in[4];
  const float* WV = (const float*)d_in[5];
  const float* bV = (const float*)d_in[6];
  float* out = (float*)d_out;

  // feat [16384,512] lives in the (yet-unwritten) output buffer; it is dead
  // before woodbury_sqrtm starts writing out. invD2+V live in d_ws (~19 MB).
  float* feat = out;
  float* invD2 = (float*)d_ws;                  // [16384,32]
  float* V = (float*)d_ws + (size_t)16384 * 32; // [16384,256] = [B,Y,K]

  // feat = relu(x @ W1 + b1)
  gemm_act<1><<<dim3(512 / 64, 16384 / 64), 256, 0, stream>>>(
      x, W1, b1, feat, 16384, 512, 128);
  // invD2 = 1/(softplus(feat@WD+bD)+1e-3)^2
  gemm_act<2><<<dim3(1, 16384 / 64), 256, 0, stream>>>(
      feat, WD, bD, invD2, 16384, 32, 512);
  // V = feat @ WV + bV
  gemm_act<0><<<dim3(256 / 64, 16384 / 64), 256, 0, stream>>>(
      feat, WV, bV, V, 16384, 256, 512);
  // per-batch Woodbury + Jacobi eigh + Q sqrt(L) Q^T
  woodbury_sqrtm<<<16384, 64, 0, stream>>>(invD2, V, out);
}

// Round 2
// 1003.938 us; speedup vs baseline: 3.9139x; 3.9139x over previous
//
#include <hip/hip_runtime.h>
#include <math.h>

// Problem constants: B=16384, IN=128, H=512, Y=32, K=8
// out = sqrtm(Sigma_inv + 1e-6 I) per batch, [16384,32,32] fp32

// ---------------------------------------------------------------------------
// Generic tiled fp32 GEMM: C[M,N] = act(A[M,K] @ B[K,N] + bias)
// ACT: 0=none, 1=relu, 2=softplus -> store 1/(D*D) with D = softplus(z)+1e-3
// ---------------------------------------------------------------------------
template <int ACT>
__global__ __launch_bounds__(256) void gemm_act(const float* __restrict__ A,
                                                const float* __restrict__ Bm,
                                                const float* __restrict__ bias,
                                                float* __restrict__ C,
                                                int M, int N, int K) {
  __shared__ float As[16][68];
  __shared__ float Bs[16][68];
  const int tid = threadIdx.x;
  const int bm = blockIdx.y * 64;
  const int bn = blockIdx.x * 64;
  const int tx = tid & 15, ty = tid >> 4;
  const int arow = tid >> 2, acol4 = (tid & 3) << 2;
  const int brow = tid >> 4, bcol4 = (tid & 15) << 2;
  float acc[4][4] = {};

  for (int k0 = 0; k0 < K; k0 += 16) {
    float4 av = *(const float4*)(A + (size_t)(bm + arow) * K + (k0 + acol4));
    As[acol4 + 0][arow] = av.x;
    As[acol4 + 1][arow] = av.y;
    As[acol4 + 2][arow] = av.z;
    As[acol4 + 3][arow] = av.w;
    float4 bv = make_float4(0.f, 0.f, 0.f, 0.f);
    if (bn + bcol4 < N)
      bv = *(const float4*)(Bm + (size_t)(k0 + brow) * N + (bn + bcol4));
    *(float4*)&Bs[brow][bcol4] = bv;
    __syncthreads();
#pragma unroll
    for (int k = 0; k < 16; ++k) {
      float ar[4], br[4];
#pragma unroll
      for (int i = 0; i < 4; ++i) ar[i] = As[k][(ty << 2) + i];
#pragma unroll
      for (int j = 0; j < 4; ++j) br[j] = Bs[k][(tx << 2) + j];
#pragma unroll
      for (int i = 0; i < 4; ++i)
#pragma unroll
        for (int j = 0; j < 4; ++j) acc[i][j] = fmaf(ar[i], br[j], acc[i][j]);
    }
    __syncthreads();
  }

#pragma unroll
  for (int i = 0; i < 4; ++i) {
    int row = bm + (ty << 2) + i;
#pragma unroll
    for (int j = 0; j < 4; ++j) {
      int col = bn + (tx << 2) + j;
      if (col < N) {
        float v = acc[i][j] + bias[col];
        if (ACT == 1) v = fmaxf(v, 0.f);
        if (ACT == 2) {
          float sp = fmaxf(v, 0.f) + log1pf(expf(-fabsf(v)));
          float D = sp + 1e-3f;
          v = 1.f / (D * D);
        }
        C[(size_t)row * N + col] = v;
      }
    }
  }
}

// ---------------------------------------------------------------------------
// One-sided (Hestenes) Jacobi, column-per-lane in registers.
// One wave = 2 batches (lanes 0-31 batch 2b, lanes 32-63 batch 2b+1).
// Setup (double-precision Woodbury) and epilogue (out = F F^T) use LDS
// one-time; the 248-round Jacobi loop is pure VGPR + ds_bpermute, no
// barriers, no LDS storage.
// ---------------------------------------------------------------------------
__global__ __launch_bounds__(64) void woodbury_sqrtm_os(
    const float* __restrict__ invD2g, const float* __restrict__ Vg,
    float* __restrict__ out) {
  const int lane = threadIdx.x;
  const int h = lane >> 5;   // which batch of the pair
  const int j = lane & 31;   // logical column index
  const int b = blockIdx.x * 2 + h;

  // LDS: stage-1 (setup) and stage-3 (epilogue) alias.
  // stage1: Vb f32[2][32][8] @0 (2048) | ad f32[2][32] @2048 (256)
  //         Md f64[2][8][9] @2304 (1152) | Ud f64[2][32][9] @3456 (4608)
  // stage3: FT f32[2][32][36] @0 (9216)
  __shared__ __align__(16) char lds[9216];
  float* Vb = (float*)lds;               // [2][32][8]
  float* ad = (float*)(lds + 2048);      // [2][32]
  double* Md = (double*)(lds + 2304);    // [2][8][9]
  double* Ud = (double*)(lds + 3456);    // [2][32][9]
  float* FT = (float*)lds;               // [2][32][36]

  // ---- load inputs ----
  const float a_d = invD2g[(size_t)b * 32 + j];
  const float4 v0 = *(const float4*)(Vg + (size_t)b * 256 + j * 8);
  const float4 v1 = *(const float4*)(Vg + (size_t)b * 256 + j * 8 + 4);
  {
    float* vb = Vb + (h * 32 + j) * 8;
    *(float4*)vb = v0;
    *(float4*)(vb + 4) = v1;
    ad[h * 32 + j] = a_d;
  }
  __syncthreads();

  // ---- M = I + V^T diag(invD2) V  (8x8, 2 entries per lane, double) ----
  {
    const int e0 = 2 * j;              // entries e0, e0+1 (same row i0)
    const int i0 = e0 >> 3, c0 = e0 & 7;
    double m0 = (i0 == c0) ? 1.0 : 0.0;
    double m1 = (i0 == c0 + 1) ? 1.0 : 0.0;
    const float* vbase = Vb + h * 256;
    const float* abase = ad + h * 32;
    for (int y = 0; y < 32; ++y) {
      double dv = (double)abase[y];
      double vi = (double)vbase[y * 8 + i0] * dv;
      m0 += vi * (double)vbase[y * 8 + c0];
      m1 += vi * (double)vbase[y * 8 + c0 + 1];
    }
    Md[h * 72 + i0 * 9 + c0] = m0;
    Md[h * 72 + i0 * 9 + c0 + 1] = m1;
  }
  __syncthreads();

  // ---- Cholesky M = L L^T in place (lower triangle), serial per batch ----
  if (j == 0) {
    double* M = Md + h * 72;
    for (int k = 0; k < 8; ++k) {
      double d = M[k * 9 + k];
      for (int i2 = 0; i2 < k; ++i2) {
        double l = M[k * 9 + i2];
        d -= l * l;
      }
      double lkk = sqrt(fmax(d, 1e-30));
      M[k * 9 + k] = lkk;
      double inv = 1.0 / lkk;
      for (int r = k + 1; r < 8; ++r) {
        double vv = M[r * 9 + k];
        for (int i2 = 0; i2 < k; ++i2) vv -= M[r * 9 + i2] * M[k * 9 + i2];
        M[r * 9 + k] = vv * inv;
      }
    }
  }
  __syncthreads();

  // ---- U = W L^{-T}, row j per lane (W row j = V row j * invD2[j]) ----
  double u[8];
  {
    const double* L = Md + h * 72;
    float w[8] = {v0.x * a_d, v0.y * a_d, v0.z * a_d, v0.w * a_d,
                  v1.x * a_d, v1.y * a_d, v1.z * a_d, v1.w * a_d};
#pragma unroll
    for (int jj = 0; jj < 8; ++jj) {
      double vv = (double)w[jj];
      for (int i2 = 0; i2 < jj; ++i2) vv -= u[i2] * L[jj * 9 + i2];
      u[jj] = vv / L[jj * 9 + jj];
    }
    double* ur = Ud + (h * 32 + j) * 9;
#pragma unroll
    for (int k = 0; k < 8; ++k) ur[k] = u[k];
  }
  __syncthreads();

  // ---- G column j in registers: G[i][j] = d_ij(invD2_i+eps) - (U U^T)_ij --
  float g[32];
#pragma unroll
  for (int i = 0; i < 32; ++i) {
    const double* ui = Ud + (h * 32 + i) * 9;
    double acc = 0.0;
#pragma unroll
    for (int k = 0; k < 8; ++k) acc += ui[k] * u[k];
    double val = -acc;
    if (i == j) val += (double)a_d + 1e-6;  // EPS folded into spectrum
    g[i] = (float)val;
  }
  __syncthreads();  // setup LDS dead; safe to alias with FT later

  // ---- one-sided Jacobi: XOR pair ordering, 8 sweeps x 31 rounds ----
  float bnorm = 0.f;
  for (int sweep = 0; sweep < 8; ++sweep) {
    // refresh own column norm^2 (kills incremental drift)
    bnorm = 0.f;
#pragma unroll
    for (int k = 0; k < 32; ++k) bnorm = fmaf(g[k], g[k], bnorm);
    for (int m = 1; m < 32; ++m) {
      const int partner = lane ^ m;       // stays within the 32-lane half
      const bool isp = j < (j ^ m);       // this lane is column p of the pair
      float pb = __shfl(bnorm, partner, 64);
      float pg[32];
#pragma unroll
      for (int k = 0; k < 32; ++k) pg[k] = __shfl(g[k], partner, 64);
      float apq = 0.f;
#pragma unroll
      for (int k = 0; k < 32; ++k) apq = fmaf(g[k], pg[k], apq);
      const float app = isp ? bnorm : pb;
      const float aqq = isp ? pb : bnorm;
      // rotation params — identical on both lanes of the pair (branchless)
      const bool big = fabsf(apq) > 1e-30f;
      const float sapq = big ? apq : 1.f;
      const float tau = (aqq - app) / (2.f * sapq);
      float t = copysignf(1.f, tau) / (fabsf(tau) + sqrtf(fmaf(tau, tau, 1.f)));
      t = big ? t : 0.f;
      const float c = 1.f / sqrtf(fmaf(t, t, 1.f));
      const float s = t * c;
      // lane p: g' = c g - s pg ; lane q: g' = c g + s pg
      const float se = isp ? -s : s;
#pragma unroll
      for (int k = 0; k < 32; ++k) g[k] = fmaf(se, pg[k], c * g[k]);
      // Jacobi diagonal identity: b_p' = b_p - t*apq, b_q' = b_q + t*apq
      bnorm = fmaxf(isp ? fmaf(-t, apq, bnorm) : fmaf(t, apq, bnorm), 0.f);
    }
  }

  // ---- epilogue: lambda_k = ||g_k||, out = sum_k lam^{-3/2} g g^T = F F^T --
  float b2 = 0.f;
#pragma unroll
  for (int k = 0; k < 32; ++k) b2 = fmaf(g[k], g[k], b2);
  b2 = fmaxf(b2, 1e-20f);
  const float lam = sqrtf(b2);
  const float sw = 1.f / sqrtf(lam * sqrtf(lam));  // lam^{-3/4}

  float* FTh = FT + h * 1152;  // [32][36], row i = (f_k[i])_k
#pragma unroll
  for (int i = 0; i < 32; ++i) FTh[i * 36 + j] = g[i] * sw;
  __syncthreads();

  // own row j into registers
  float rj[32];
  {
    const float4* rowj = (const float4*)(FTh + j * 36);
#pragma unroll
    for (int c4 = 0; c4 < 8; ++c4) {
      float4 v = rowj[c4];
      rj[4 * c4 + 0] = v.x;
      rj[4 * c4 + 1] = v.y;
      rj[4 * c4 + 2] = v.z;
      rj[4 * c4 + 3] = v.w;
    }
  }
  float* ob = out + (size_t)b * 1024;
  for (int i = 0; i < 32; ++i) {
    const float4* rowi = (const float4*)(FTh + i * 36);
    float acc = 0.f;
#pragma unroll
    for (int c4 = 0; c4 < 8; ++c4) {
      float4 v = rowi[c4];  // broadcast read
      acc = fmaf(v.x, rj[4 * c4 + 0], acc);
      acc = fmaf(v.y, rj[4 * c4 + 1], acc);
      acc = fmaf(v.z, rj[4 * c4 + 2], acc);
      acc = fmaf(v.w, rj[4 * c4 + 3], acc);
    }
    ob[i * 32 + j] = acc;  // coalesced
  }
}

// ---------------------------------------------------------------------------
extern "C" void kernel_launch(void* const* d_in, const int* in_sizes, int n_in,
                              void* d_out, int out_size, void* d_ws,
                              size_t ws_size, hipStream_t stream) {
  const float* x = (const float*)d_in[0];
  const float* W1 = (const float*)d_in[1];
  const float* b1 = (const float*)d_in[2];
  const float* WD = (const float*)d_in[3];
  const float* bD = (const float*)d_in[4];
  const float* WV = (const float*)d_in[5];
  const float* bV = (const float*)d_in[6];
  float* out = (float*)d_out;

  float* feat = out;                             // [16384,512] dead before out
  float* invD2 = (float*)d_ws;                   // [16384,32]
  float* V = (float*)d_ws + (size_t)16384 * 32;  // [16384,256]

  gemm_act<1><<<dim3(512 / 64, 16384 / 64), 256, 0, stream>>>(
      x, W1, b1, feat, 16384, 512, 128);
  gemm_act<2><<<dim3(1, 16384 / 64), 256, 0, stream>>>(
      feat, WD, bD, invD2, 16384, 32, 512);
  gemm_act<0><<<dim3(256 / 64, 16384 / 64), 256, 0, stream>>>(
      feat, WV, bV, V, 16384, 256, 512);
  woodbury_sqrtm_os<<<16384 / 2, 64, 0, stream>>>(invD2, V, out);
}

// Round 3
// 904.454 us; speedup vs baseline: 4.3444x; 1.1100x over previous
//
#include <hip/hip_runtime.h>
#include <math.h>

// Problem constants: B=16384, IN=128, H=512, Y=32, K=8
// out = sqrtm(Sigma_inv + 1e-6 I) per batch, [16384,32,32] fp32

// ---------------------------------------------------------------------------
// Generic tiled fp32 GEMM: C[M,N] = act(A[M,K] @ B[K,N] + bias)
// ACT: 0=none, 1=relu, 2=softplus -> store 1/(D*D) with D = softplus(z)+1e-3
// ---------------------------------------------------------------------------
template <int ACT>
__global__ __launch_bounds__(256) void gemm_act(const float* __restrict__ A,
                                                const float* __restrict__ Bm,
                                                const float* __restrict__ bias,
                                                float* __restrict__ C,
                                                int M, int N, int K) {
  __shared__ float As[16][68];
  __shared__ float Bs[16][68];
  const int tid = threadIdx.x;
  const int bm = blockIdx.y * 64;
  const int bn = blockIdx.x * 64;
  const int tx = tid & 15, ty = tid >> 4;
  const int arow = tid >> 2, acol4 = (tid & 3) << 2;
  const int brow = tid >> 4, bcol4 = (tid & 15) << 2;
  float acc[4][4] = {};

  for (int k0 = 0; k0 < K; k0 += 16) {
    float4 av = *(const float4*)(A + (size_t)(bm + arow) * K + (k0 + acol4));
    As[acol4 + 0][arow] = av.x;
    As[acol4 + 1][arow] = av.y;
    As[acol4 + 2][arow] = av.z;
    As[acol4 + 3][arow] = av.w;
    float4 bv = make_float4(0.f, 0.f, 0.f, 0.f);
    if (bn + bcol4 < N)
      bv = *(const float4*)(Bm + (size_t)(k0 + brow) * N + (bn + bcol4));
    *(float4*)&Bs[brow][bcol4] = bv;
    __syncthreads();
#pragma unroll
    for (int k = 0; k < 16; ++k) {
      float ar[4], br[4];
#pragma unroll
      for (int i = 0; i < 4; ++i) ar[i] = As[k][(ty << 2) + i];
#pragma unroll
      for (int j = 0; j < 4; ++j) br[j] = Bs[k][(tx << 2) + j];
#pragma unroll
      for (int i = 0; i < 4; ++i)
#pragma unroll
        for (int j = 0; j < 4; ++j) acc[i][j] = fmaf(ar[i], br[j], acc[i][j]);
    }
    __syncthreads();
  }

#pragma unroll
  for (int i = 0; i < 4; ++i) {
    int row = bm + (ty << 2) + i;
#pragma unroll
    for (int j = 0; j < 4; ++j) {
      int col = bn + (tx << 2) + j;
      if (col < N) {
        float v = acc[i][j] + bias[col];
        if (ACT == 1) v = fmaxf(v, 0.f);
        if (ACT == 2) {
          float sp = fmaxf(v, 0.f) + log1pf(expf(-fabsf(v)));
          float D = sp + 1e-3f;
          v = 1.f / (D * D);
        }
        C[(size_t)row * N + col] = v;
      }
    }
  }
}

// ---------------------------------------------------------------------------
// One-sided (Hestenes) Jacobi, column-per-lane in registers.
// One wave = 2 batches (lanes 0-31 batch 2b, lanes 32-63 batch 2b+1).
// __launch_bounds__(64, 4): 4 waves/EU -> 128-VGPR budget so the partner
// column pg[32] stays register-resident (at the default budget the compiler
// allocated 48 VGPRs and re-issued every ds_bpermute twice per round).
// Occupancy is WG-slot/LDS capped at 16 waves/CU anyway.
// ---------------------------------------------------------------------------
__global__ __launch_bounds__(64, 4) void woodbury_sqrtm_os(
    const float* __restrict__ invD2g, const float* __restrict__ Vg,
    float* __restrict__ out) {
  const int lane = threadIdx.x;
  const int h = lane >> 5;   // which batch of the pair
  const int j = lane & 31;   // logical column index
  const int b = blockIdx.x * 2 + h;

  // LDS: stage-1 (setup) and stage-3 (epilogue) alias.
  __shared__ __align__(16) char lds[9216];
  float* Vb = (float*)lds;               // [2][32][8]
  float* ad = (float*)(lds + 2048);      // [2][32]
  double* Md = (double*)(lds + 2304);    // [2][8][9]
  double* Ud = (double*)(lds + 3456);    // [2][32][9]
  float* FT = (float*)lds;               // [2][32][36]

  // ---- load inputs ----
  const float a_d = invD2g[(size_t)b * 32 + j];
  const float4 v0 = *(const float4*)(Vg + (size_t)b * 256 + j * 8);
  const float4 v1 = *(const float4*)(Vg + (size_t)b * 256 + j * 8 + 4);
  {
    float* vb = Vb + (h * 32 + j) * 8;
    *(float4*)vb = v0;
    *(float4*)(vb + 4) = v1;
    ad[h * 32 + j] = a_d;
  }
  __syncthreads();

  // ---- M = I + V^T diag(invD2) V  (8x8, 2 entries per lane, double) ----
  {
    const int e0 = 2 * j;
    const int i0 = e0 >> 3, c0 = e0 & 7;
    double m0 = (i0 == c0) ? 1.0 : 0.0;
    double m1 = (i0 == c0 + 1) ? 1.0 : 0.0;
    const float* vbase = Vb + h * 256;
    const float* abase = ad + h * 32;
    for (int y = 0; y < 32; ++y) {
      double dv = (double)abase[y];
      double vi = (double)vbase[y * 8 + i0] * dv;
      m0 += vi * (double)vbase[y * 8 + c0];
      m1 += vi * (double)vbase[y * 8 + c0 + 1];
    }
    Md[h * 72 + i0 * 9 + c0] = m0;
    Md[h * 72 + i0 * 9 + c0 + 1] = m1;
  }
  __syncthreads();

  // ---- Cholesky M = L L^T in place, serial per batch (tiny) ----
  if (j == 0) {
    double* M = Md + h * 72;
    for (int k = 0; k < 8; ++k) {
      double d = M[k * 9 + k];
      for (int i2 = 0; i2 < k; ++i2) {
        double l = M[k * 9 + i2];
        d -= l * l;
      }
      double lkk = sqrt(fmax(d, 1e-30));
      M[k * 9 + k] = lkk;
      double inv = 1.0 / lkk;
      for (int r = k + 1; r < 8; ++r) {
        double vv = M[r * 9 + k];
        for (int i2 = 0; i2 < k; ++i2) vv -= M[r * 9 + i2] * M[k * 9 + i2];
        M[r * 9 + k] = vv * inv;
      }
    }
  }
  __syncthreads();

  // ---- U = W L^{-T}, row j per lane (W row j = V row j * invD2[j]) ----
  double u[8];
  {
    const double* L = Md + h * 72;
    float w[8] = {v0.x * a_d, v0.y * a_d, v0.z * a_d, v0.w * a_d,
                  v1.x * a_d, v1.y * a_d, v1.z * a_d, v1.w * a_d};
#pragma unroll
    for (int jj = 0; jj < 8; ++jj) {
      double vv = (double)w[jj];
      for (int i2 = 0; i2 < jj; ++i2) vv -= u[i2] * L[jj * 9 + i2];
      u[jj] = vv / L[jj * 9 + jj];
    }
    double* ur = Ud + (h * 32 + j) * 9;
#pragma unroll
    for (int k = 0; k < 8; ++k) ur[k] = u[k];
  }
  __syncthreads();

  // ---- G column j in registers: G[i][j] = d_ij(invD2_i+eps) - (U U^T)_ij --
  float g[32];
#pragma unroll
  for (int i = 0; i < 32; ++i) {
    const double* ui = Ud + (h * 32 + i) * 9;
    double acc = 0.0;
#pragma unroll
    for (int k = 0; k < 8; ++k) acc += ui[k] * u[k];
    double val = -acc;
    if (i == j) val += (double)a_d + 1e-6;  // EPS folded into spectrum
    g[i] = (float)val;
  }
  __syncthreads();  // setup LDS dead; safe to alias with FT later

  // ---- one-sided Jacobi: XOR pair ordering, 7 sweeps x 31 rounds ----
  float bnorm = 0.f;
  for (int sweep = 0; sweep < 7; ++sweep) {
    // refresh own column norm^2 (kills incremental drift); 4-way ILP
    {
      float n0 = 0.f, n1 = 0.f, n2 = 0.f, n3 = 0.f;
#pragma unroll
      for (int k = 0; k < 32; k += 4) {
        n0 = fmaf(g[k + 0], g[k + 0], n0);
        n1 = fmaf(g[k + 1], g[k + 1], n1);
        n2 = fmaf(g[k + 2], g[k + 2], n2);
        n3 = fmaf(g[k + 3], g[k + 3], n3);
      }
      bnorm = (n0 + n1) + (n2 + n3);
    }
    for (int m = 1; m < 32; ++m) {
      const int partner = lane ^ m;       // stays within the 32-lane half
      const bool isp = j < (j ^ m);       // this lane is column p of the pair
      // pull partner column ONCE into registers (single ds_bpermute pass)
      float pg[32];
#pragma unroll
      for (int k = 0; k < 32; ++k) pg[k] = __shfl(g[k], partner, 64);
      const float pb = __shfl(bnorm, partner, 64);
      // dot(g, pg) with 4-way split accumulators
      float d0 = 0.f, d1 = 0.f, d2 = 0.f, d3 = 0.f;
#pragma unroll
      for (int k = 0; k < 32; k += 4) {
        d0 = fmaf(g[k + 0], pg[k + 0], d0);
        d1 = fmaf(g[k + 1], pg[k + 1], d1);
        d2 = fmaf(g[k + 2], pg[k + 2], d2);
        d3 = fmaf(g[k + 3], pg[k + 3], d3);
      }
      const float apq = (d0 + d1) + (d2 + d3);
      const float app = isp ? bnorm : pb;
      const float aqq = isp ? pb : bnorm;
      // rotation params — identical on both lanes of the pair (branchless)
      const bool big = fabsf(apq) > 1e-30f;
      const float sapq = big ? apq : 1.f;
      const float tau = (aqq - app) / (2.f * sapq);
      float t = copysignf(1.f, tau) / (fabsf(tau) + sqrtf(fmaf(tau, tau, 1.f)));
      t = big ? t : 0.f;
      const float c = 1.f / sqrtf(fmaf(t, t, 1.f));
      const float s = t * c;
      // lane p: g' = c g - s pg ; lane q: g' = c g + s pg
      const float se = isp ? -s : s;
#pragma unroll
      for (int k = 0; k < 32; ++k) g[k] = fmaf(se, pg[k], c * g[k]);
      // Jacobi diagonal identity: b_p' = b_p - t*apq, b_q' = b_q + t*apq
      bnorm = fmaxf(isp ? fmaf(-t, apq, bnorm) : fmaf(t, apq, bnorm), 0.f);
    }
  }

  // ---- epilogue: lambda_k = ||g_k||, out = sum_k lam^{-3/2} g g^T = F F^T --
  float b2;
  {
    float n0 = 0.f, n1 = 0.f, n2 = 0.f, n3 = 0.f;
#pragma unroll
    for (int k = 0; k < 32; k += 4) {
      n0 = fmaf(g[k + 0], g[k + 0], n0);
      n1 = fmaf(g[k + 1], g[k + 1], n1);
      n2 = fmaf(g[k + 2], g[k + 2], n2);
      n3 = fmaf(g[k + 3], g[k + 3], n3);
    }
    b2 = fmaxf((n0 + n1) + (n2 + n3), 1e-20f);
  }
  const float lam = sqrtf(b2);
  const float sw = 1.f / sqrtf(lam * sqrtf(lam));  // lam^{-3/4}

  float* FTh = FT + h * 1152;  // [32][36], row i = (f_k[i])_k
#pragma unroll
  for (int i = 0; i < 32; ++i) FTh[i * 36 + j] = g[i] * sw;
  __syncthreads();

  // own row j into registers
  float rj[32];
  {
    const float4* rowj = (const float4*)(FTh + j * 36);
#pragma unroll
    for (int c4 = 0; c4 < 8; ++c4) {
      float4 v = rowj[c4];
      rj[4 * c4 + 0] = v.x;
      rj[4 * c4 + 1] = v.y;
      rj[4 * c4 + 2] = v.z;
      rj[4 * c4 + 3] = v.w;
    }
  }
  float* ob = out + (size_t)b * 1024;
  for (int i = 0; i < 32; ++i) {
    const float4* rowi = (const float4*)(FTh + i * 36);
    float acc = 0.f;
#pragma unroll
    for (int c4 = 0; c4 < 8; ++c4) {
      float4 v = rowi[c4];  // broadcast read
      acc = fmaf(v.x, rj[4 * c4 + 0], acc);
      acc = fmaf(v.y, rj[4 * c4 + 1], acc);
      acc = fmaf(v.z, rj[4 * c4 + 2], acc);
      acc = fmaf(v.w, rj[4 * c4 + 3], acc);
    }
    ob[i * 32 + j] = acc;  // coalesced
  }
}

// ---------------------------------------------------------------------------
extern "C" void kernel_launch(void* const* d_in, const int* in_sizes, int n_in,
                              void* d_out, int out_size, void* d_ws,
                              size_t ws_size, hipStream_t stream) {
  const float* x = (const float*)d_in[0];
  const float* W1 = (const float*)d_in[1];
  const float* b1 = (const float*)d_in[2];
  const float* WD = (const float*)d_in[3];
  const float* bD = (const float*)d_in[4];
  const float* WV = (const float*)d_in[5];
  const float* bV = (const float*)d_in[6];
  float* out = (float*)d_out;

  float* feat = out;                             // [16384,512] dead before out
  float* invD2 = (float*)d_ws;                   // [16384,32]
  float* V = (float*)d_ws + (size_t)16384 * 32;  // [16384,256]

  gemm_act<1><<<dim3(512 / 64, 16384 / 64), 256, 0, stream>>>(
      x, W1, b1, feat, 16384, 512, 128);
  gemm_act<2><<<dim3(1, 16384 / 64), 256, 0, stream>>>(
      feat, WD, bD, invD2, 16384, 32, 512);
  gemm_act<0><<<dim3(256 / 64, 16384 / 64), 256, 0, stream>>>(
      feat, WV, bV, V, 16384, 256, 512);
  woodbury_sqrtm_os<<<16384 / 2, 64, 0, stream>>>(invD2, V, out);
}

// Round 4
// 885.260 us; speedup vs baseline: 4.4386x; 1.0217x over previous
//
#include <hip/hip_runtime.h>
#include <math.h>

// Problem constants: B=16384, IN=128, H=512, Y=32, K=8
// out = sqrtm(Sigma_inv + 1e-6 I) per batch, [16384,32,32] fp32

typedef float v2f __attribute__((ext_vector_type(2)));

// ---------------------------------------------------------------------------
// Generic tiled fp32 GEMM: C[M,N] = act(A[M,K] @ B[K,N] + bias)
// ACT: 0=none, 1=relu, 2=softplus -> store 1/(D*D) with D = softplus(z)+1e-3
// ---------------------------------------------------------------------------
template <int ACT>
__global__ __launch_bounds__(256) void gemm_act(const float* __restrict__ A,
                                                const float* __restrict__ Bm,
                                                const float* __restrict__ bias,
                                                float* __restrict__ C,
                                                int M, int N, int K) {
  __shared__ float As[16][68];
  __shared__ float Bs[16][68];
  const int tid = threadIdx.x;
  const int bm = blockIdx.y * 64;
  const int bn = blockIdx.x * 64;
  const int tx = tid & 15, ty = tid >> 4;
  const int arow = tid >> 2, acol4 = (tid & 3) << 2;
  const int brow = tid >> 4, bcol4 = (tid & 15) << 2;
  float acc[4][4] = {};

  for (int k0 = 0; k0 < K; k0 += 16) {
    float4 av = *(const float4*)(A + (size_t)(bm + arow) * K + (k0 + acol4));
    As[acol4 + 0][arow] = av.x;
    As[acol4 + 1][arow] = av.y;
    As[acol4 + 2][arow] = av.z;
    As[acol4 + 3][arow] = av.w;
    float4 bv = make_float4(0.f, 0.f, 0.f, 0.f);
    if (bn + bcol4 < N)
      bv = *(const float4*)(Bm + (size_t)(k0 + brow) * N + (bn + bcol4));
    *(float4*)&Bs[brow][bcol4] = bv;
    __syncthreads();
#pragma unroll
    for (int k = 0; k < 16; ++k) {
      float ar[4], br[4];
#pragma unroll
      for (int i = 0; i < 4; ++i) ar[i] = As[k][(ty << 2) + i];
#pragma unroll
      for (int j = 0; j < 4; ++j) br[j] = Bs[k][(tx << 2) + j];
#pragma unroll
      for (int i = 0; i < 4; ++i)
#pragma unroll
        for (int j = 0; j < 4; ++j) acc[i][j] = fmaf(ar[i], br[j], acc[i][j]);
    }
    __syncthreads();
  }

#pragma unroll
  for (int i = 0; i < 4; ++i) {
    int row = bm + (ty << 2) + i;
#pragma unroll
    for (int j = 0; j < 4; ++j) {
      int col = bn + (tx << 2) + j;
      if (col < N) {
        float v = acc[i][j] + bias[col];
        if (ACT == 1) v = fmaxf(v, 0.f);
        if (ACT == 2) {
          float sp = fmaxf(v, 0.f) + log1pf(expf(-fabsf(v)));
          float D = sp + 1e-3f;
          v = 1.f / (D * D);
        }
        C[(size_t)row * N + col] = v;
      }
    }
  }
}

// ---------------------------------------------------------------------------
// One-sided (Hestenes) Jacobi, column-per-lane in registers (float2-packed).
// One wave = 2 batches (lanes 0-31 batch 2b, lanes 32-63 batch 2b+1).
// Partner-column exchange: raw ds_bpermute (no __shfl mask math).
// Arithmetic in float2 ext-vectors -> v_pk_fma_f32 (2x fp32/inst).
// __launch_bounds__(64, 2): 256-VGPR budget so g2[16]+pg2[16] (64 VGPRs)
// stay register-resident; at tighter budgets the allocator shuttled the
// partner column through AGPRs (v_accvgpr_* = VALU) -> 480 VALU/round.
// ---------------------------------------------------------------------------
__global__ __launch_bounds__(64, 2) void woodbury_sqrtm_os(
    const float* __restrict__ invD2g, const float* __restrict__ Vg,
    float* __restrict__ out) {
  const int lane = threadIdx.x;
  const int h = lane >> 5;   // which batch of the pair
  const int j = lane & 31;   // logical column index
  const int b = blockIdx.x * 2 + h;

  // LDS: stage-1 (setup) and stage-3 (epilogue) alias.
  __shared__ __align__(16) char lds[9216];
  float* Vb = (float*)lds;               // [2][32][8]
  float* ad = (float*)(lds + 2048);      // [2][32]
  double* Md = (double*)(lds + 2304);    // [2][8][9]
  double* Ud = (double*)(lds + 3456);    // [2][32][9]
  float* FT = (float*)lds;               // [2][32][36]

  // ---- load inputs ----
  const float a_d = invD2g[(size_t)b * 32 + j];
  const float4 v0 = *(const float4*)(Vg + (size_t)b * 256 + j * 8);
  const float4 v1 = *(const float4*)(Vg + (size_t)b * 256 + j * 8 + 4);
  {
    float* vb = Vb + (h * 32 + j) * 8;
    *(float4*)vb = v0;
    *(float4*)(vb + 4) = v1;
    ad[h * 32 + j] = a_d;
  }
  __syncthreads();

  // ---- M = I + V^T diag(invD2) V  (8x8, 2 entries per lane, double) ----
  {
    const int e0 = 2 * j;
    const int i0 = e0 >> 3, c0 = e0 & 7;
    double m0 = (i0 == c0) ? 1.0 : 0.0;
    double m1 = (i0 == c0 + 1) ? 1.0 : 0.0;
    const float* vbase = Vb + h * 256;
    const float* abase = ad + h * 32;
    for (int y = 0; y < 32; ++y) {
      double dv = (double)abase[y];
      double vi = (double)vbase[y * 8 + i0] * dv;
      m0 += vi * (double)vbase[y * 8 + c0];
      m1 += vi * (double)vbase[y * 8 + c0 + 1];
    }
    Md[h * 72 + i0 * 9 + c0] = m0;
    Md[h * 72 + i0 * 9 + c0 + 1] = m1;
  }
  __syncthreads();

  // ---- Cholesky M = L L^T in place, serial per batch (tiny) ----
  if (j == 0) {
    double* M = Md + h * 72;
    for (int k = 0; k < 8; ++k) {
      double d = M[k * 9 + k];
      for (int i2 = 0; i2 < k; ++i2) {
        double l = M[k * 9 + i2];
        d -= l * l;
      }
      double lkk = sqrt(fmax(d, 1e-30));
      M[k * 9 + k] = lkk;
      double inv = 1.0 / lkk;
      for (int r = k + 1; r < 8; ++r) {
        double vv = M[r * 9 + k];
        for (int i2 = 0; i2 < k; ++i2) vv -= M[r * 9 + i2] * M[k * 9 + i2];
        M[r * 9 + k] = vv * inv;
      }
    }
  }
  __syncthreads();

  // ---- U = W L^{-T}, row j per lane (W row j = V row j * invD2[j]) ----
  double u[8];
  {
    const double* L = Md + h * 72;
    float w[8] = {v0.x * a_d, v0.y * a_d, v0.z * a_d, v0.w * a_d,
                  v1.x * a_d, v1.y * a_d, v1.z * a_d, v1.w * a_d};
#pragma unroll
    for (int jj = 0; jj < 8; ++jj) {
      double vv = (double)w[jj];
      for (int i2 = 0; i2 < jj; ++i2) vv -= u[i2] * L[jj * 9 + i2];
      u[jj] = vv / L[jj * 9 + jj];
    }
    double* ur = Ud + (h * 32 + j) * 9;
#pragma unroll
    for (int k = 0; k < 8; ++k) ur[k] = u[k];
  }
  __syncthreads();

  // ---- G column j: G[i][j] = d_ij(invD2_i+eps) - (U U^T)_ij, f2-packed ----
  v2f g2[16];
#pragma unroll
  for (int i = 0; i < 32; ++i) {
    const double* ui = Ud + (h * 32 + i) * 9;
    double acc = 0.0;
#pragma unroll
    for (int k = 0; k < 8; ++k) acc += ui[k] * u[k];
    double val = -acc;
    if (i == j) val += (double)a_d + 1e-6;  // EPS folded into spectrum
    if (i & 1)
      g2[i >> 1].y = (float)val;
    else
      g2[i >> 1].x = (float)val;
  }
  __syncthreads();  // setup LDS dead; safe to alias with FT later

  // ---- one-sided Jacobi: XOR pair ordering, 7 sweeps x 31 rounds ----
  const int lane4 = lane << 2;
  float bnorm = 0.f;
  for (int sweep = 0; sweep < 7; ++sweep) {
    // refresh own column norm^2 (kills incremental drift); packed 4-way ILP
    {
      v2f a0 = {0.f, 0.f}, a1 = {0.f, 0.f}, a2 = {0.f, 0.f}, a3 = {0.f, 0.f};
#pragma unroll
      for (int k = 0; k < 16; k += 4) {
        a0 += g2[k + 0] * g2[k + 0];
        a1 += g2[k + 1] * g2[k + 1];
        a2 += g2[k + 2] * g2[k + 2];
        a3 += g2[k + 3] * g2[k + 3];
      }
      v2f t01 = a0 + a1, t23 = a2 + a3, tt = t01 + t23;
      bnorm = tt.x + tt.y;
    }
    for (int m = 1; m < 32; ++m) {
      const int pb4 = lane4 ^ (m << 2);   // partner byte-addr for bpermute
      const bool isp = j < (j ^ m);       // this lane is column p of the pair
      // pull partner column ONCE into registers (33 raw ds_bpermute)
      v2f pg2[16];
#pragma unroll
      for (int k = 0; k < 16; ++k) {
        pg2[k].x = __int_as_float(
            __builtin_amdgcn_ds_bpermute(pb4, __float_as_int(g2[k].x)));
        pg2[k].y = __int_as_float(
            __builtin_amdgcn_ds_bpermute(pb4, __float_as_int(g2[k].y)));
      }
      const float pb = __int_as_float(
          __builtin_amdgcn_ds_bpermute(pb4, __float_as_int(bnorm)));
      // dot(g, pg), packed with 4-way split accumulators
      v2f d0 = {0.f, 0.f}, d1 = {0.f, 0.f}, d2 = {0.f, 0.f}, d3 = {0.f, 0.f};
#pragma unroll
      for (int k = 0; k < 16; k += 4) {
        d0 += g2[k + 0] * pg2[k + 0];
        d1 += g2[k + 1] * pg2[k + 1];
        d2 += g2[k + 2] * pg2[k + 2];
        d3 += g2[k + 3] * pg2[k + 3];
      }
      v2f s01 = d0 + d1, s23 = d2 + d3, st = s01 + s23;
      const float apq = st.x + st.y;
      const float app = isp ? bnorm : pb;
      const float aqq = isp ? pb : bnorm;
      // rotation params — identical on both lanes of the pair (branchless)
      const bool big = fabsf(apq) > 1e-30f;
      const float sapq = big ? apq : 1.f;
      const float tau = (aqq - app) / (2.f * sapq);
      float t = copysignf(1.f, tau) / (fabsf(tau) + sqrtf(fmaf(tau, tau, 1.f)));
      t = big ? t : 0.f;
      const float c = 1.f / sqrtf(fmaf(t, t, 1.f));
      const float s = t * c;
      const float se = isp ? -s : s;
      const v2f cc = {c, c};
      const v2f sse = {se, se};
      // lane p: g' = c g - s pg ; lane q: g' = c g + s pg  (v_pk_fma path)
#pragma unroll
      for (int k = 0; k < 16; ++k) g2[k] = cc * g2[k] + sse * pg2[k];
      // Jacobi diagonal identity: b_p' = b_p - t*apq, b_q' = b_q + t*apq
      bnorm = fmaxf(fmaf(isp ? -t : t, apq, bnorm), 0.f);
    }
  }

  // ---- epilogue: lambda_k = ||g_k||, out = sum_k lam^{-3/2} g g^T = F F^T --
  float b2;
  {
    v2f a0 = {0.f, 0.f}, a1 = {0.f, 0.f}, a2 = {0.f, 0.f}, a3 = {0.f, 0.f};
#pragma unroll
    for (int k = 0; k < 16; k += 4) {
      a0 += g2[k + 0] * g2[k + 0];
      a1 += g2[k + 1] * g2[k + 1];
      a2 += g2[k + 2] * g2[k + 2];
      a3 += g2[k + 3] * g2[k + 3];
    }
    v2f t01 = a0 + a1, t23 = a2 + a3, tt = t01 + t23;
    b2 = fmaxf(tt.x + tt.y, 1e-20f);
  }
  const float lam = sqrtf(b2);
  const float sw = 1.f / sqrtf(lam * sqrtf(lam));  // lam^{-3/4}

  float* FTh = FT + h * 1152;  // [32][36], row i = (f_k[i])_k
#pragma unroll
  for (int i = 0; i < 16; ++i) {
    FTh[(2 * i + 0) * 36 + j] = g2[i].x * sw;
    FTh[(2 * i + 1) * 36 + j] = g2[i].y * sw;
  }
  __syncthreads();

  // own row j into registers
  float rj[32];
  {
    const float4* rowj = (const float4*)(FTh + j * 36);
#pragma unroll
    for (int c4 = 0; c4 < 8; ++c4) {
      float4 v = rowj[c4];
      rj[4 * c4 + 0] = v.x;
      rj[4 * c4 + 1] = v.y;
      rj[4 * c4 + 2] = v.z;
      rj[4 * c4 + 3] = v.w;
    }
  }
  float* ob = out + (size_t)b * 1024;
  for (int i = 0; i < 32; ++i) {
    const float4* rowi = (const float4*)(FTh + i * 36);
    float acc = 0.f;
#pragma unroll
    for (int c4 = 0; c4 < 8; ++c4) {
      float4 v = rowi[c4];  // broadcast read
      acc = fmaf(v.x, rj[4 * c4 + 0], acc);
      acc = fmaf(v.y, rj[4 * c4 + 1], acc);
      acc = fmaf(v.z, rj[4 * c4 + 2], acc);
      acc = fmaf(v.w, rj[4 * c4 + 3], acc);
    }
    ob[i * 32 + j] = acc;  // coalesced
  }
}

// ---------------------------------------------------------------------------
extern "C" void kernel_launch(void* const* d_in, const int* in_sizes, int n_in,
                              void* d_out, int out_size, void* d_ws,
                              size_t ws_size, hipStream_t stream) {
  const float* x = (const float*)d_in[0];
  const float* W1 = (const float*)d_in[1];
  const float* b1 = (const float*)d_in[2];
  const float* WD = (const float*)d_in[3];
  const float* bD = (const float*)d_in[4];
  const float* WV = (const float*)d_in[5];
  const float* bV = (const float*)d_in[6];
  float* out = (float*)d_out;

  float* feat = out;                             // [16384,512] dead before out
  float* invD2 = (float*)d_ws;                   // [16384,32]
  float* V = (float*)d_ws + (size_t)16384 * 32;  // [16384,256]

  gemm_act<1><<<dim3(512 / 64, 16384 / 64), 256, 0, stream>>>(
      x, W1, b1, feat, 16384, 512, 128);
  gemm_act<2><<<dim3(1, 16384 / 64), 256, 0, stream>>>(
      feat, WD, bD, invD2, 16384, 32, 512);
  gemm_act<0><<<dim3(256 / 64, 16384 / 64), 256, 0, stream>>>(
      feat, WV, bV, V, 16384, 256, 512);
  woodbury_sqrtm_os<<<16384 / 2, 64, 0, stream>>>(invD2, V, out);
}

// Round 5
// 808.719 us; speedup vs baseline: 4.8587x; 1.0946x over previous
//
#include <hip/hip_runtime.h>
#include <math.h>

// Problem constants: B=16384, IN=128, H=512, Y=32, K=8
// out = sqrtm(Sigma_inv + 1e-6 I) per batch, [16384,32,32] fp32

typedef float v2f __attribute__((ext_vector_type(2)));

// ---------------------------------------------------------------------------
// Generic tiled fp32 GEMM: C[M,N] = act(A[M,K] @ B[K,N] + bias)
// ACT: 0=none, 1=relu, 2=softplus -> store 1/(D*D) with D = softplus(z)+1e-3
// ---------------------------------------------------------------------------
template <int ACT>
__global__ __launch_bounds__(256) void gemm_act(const float* __restrict__ A,
                                                const float* __restrict__ Bm,
                                                const float* __restrict__ bias,
                                                float* __restrict__ C,
                                                int M, int N, int K) {
  __shared__ float As[16][68];
  __shared__ float Bs[16][68];
  const int tid = threadIdx.x;
  const int bm = blockIdx.y * 64;
  const int bn = blockIdx.x * 64;
  const int tx = tid & 15, ty = tid >> 4;
  const int arow = tid >> 2, acol4 = (tid & 3) << 2;
  const int brow = tid >> 4, bcol4 = (tid & 15) << 2;
  float acc[4][4] = {};

  for (int k0 = 0; k0 < K; k0 += 16) {
    float4 av = *(const float4*)(A + (size_t)(bm + arow) * K + (k0 + acol4));
    As[acol4 + 0][arow] = av.x;
    As[acol4 + 1][arow] = av.y;
    As[acol4 + 2][arow] = av.z;
    As[acol4 + 3][arow] = av.w;
    float4 bv = make_float4(0.f, 0.f, 0.f, 0.f);
    if (bn + bcol4 < N)
      bv = *(const float4*)(Bm + (size_t)(k0 + brow) * N + (bn + bcol4));
    *(float4*)&Bs[brow][bcol4] = bv;
    __syncthreads();
#pragma unroll
    for (int k = 0; k < 16; ++k) {
      float ar[4], br[4];
#pragma unroll
      for (int i = 0; i < 4; ++i) ar[i] = As[k][(ty << 2) + i];
#pragma unroll
      for (int j = 0; j < 4; ++j) br[j] = Bs[k][(tx << 2) + j];
#pragma unroll
      for (int i = 0; i < 4; ++i)
#pragma unroll
        for (int j = 0; j < 4; ++j) acc[i][j] = fmaf(ar[i], br[j], acc[i][j]);
    }
    __syncthreads();
  }

#pragma unroll
  for (int i = 0; i < 4; ++i) {
    int row = bm + (ty << 2) + i;
#pragma unroll
    for (int j = 0; j < 4; ++j) {
      int col = bn + (tx << 2) + j;
      if (col < N) {
        float v = acc[i][j] + bias[col];
        if (ACT == 1) v = fmaxf(v, 0.f);
        if (ACT == 2) {
          float sp = fmaxf(v, 0.f) + log1pf(expf(-fabsf(v)));
          float D = sp + 1e-3f;
          v = 1.f / (D * D);
        }
        C[(size_t)row * N + col] = v;
      }
    }
  }
}

// ---------------------------------------------------------------------------
// Block one-sided Jacobi: 2 columns per lane, 16 lanes per batch,
// 4 batches per 64-thread wave. XOR lane-pairing m=1..15 per sweep; per
// meeting: rotate own pair, pull partner's 2 columns ONCE (pinned via inline
// asm so the compiler cannot re-materialize the bpermutes), replay 4 cross
// rotations redundantly on both lanes (bit-identical: dots are commutative
// per-term, disjoint rotations commute exactly).
// ---------------------------------------------------------------------------
#define PIN2(x) asm("" : "+v"(x))

__device__ __forceinline__ float bperm1(int addr, float v) {
  return __int_as_float(__builtin_amdgcn_ds_bpermute(addr, __float_as_int(v)));
}

__device__ __forceinline__ float dotcols(const v2f* a, const v2f* b) {
  v2f d0 = {0.f, 0.f}, d1 = {0.f, 0.f}, d2 = {0.f, 0.f}, d3 = {0.f, 0.f};
#pragma unroll
  for (int k = 0; k < 16; k += 4) {
    d0 += a[k + 0] * b[k + 0];
    d1 += a[k + 1] * b[k + 1];
    d2 += a[k + 2] * b[k + 2];
    d3 += a[k + 3] * b[k + 3];
  }
  v2f s01 = d0 + d1, s23 = d2 + d3, st = s01 + s23;
  return st.x + st.y;
}

// Rotate columns O (own) and P (resident copy of the other column).
// Canonical roles: if isp, O is the p-column, else O is the q-column.
// p' = c p - s q ; q' = s p + c q ; ||p||^2 -= t*apq ; ||q||^2 += t*apq.
__device__ __forceinline__ void crossrot(v2f* O, float& nO, v2f* P, float& nP,
                                         bool isp) {
  const float apq = dotcols(O, P);
  const float app = isp ? nO : nP;
  const float aqq = isp ? nP : nO;
  const bool big = fabsf(apq) > 1e-30f;
  const float sapq = big ? apq : 1.f;
  const float tau = (aqq - app) * 0.5f * __builtin_amdgcn_rcpf(sapq);
  float t = copysignf(
      __builtin_amdgcn_rcpf(fabsf(tau) + sqrtf(fmaf(tau, tau, 1.f))), tau);
  t = big ? t : 0.f;
  const float c = __builtin_amdgcn_rsqf(fmaf(t, t, 1.f));
  const float s = t * c;
  const float se = isp ? -s : s;
  const v2f cc = {c, c};
  const v2f vse = {se, se};
#pragma unroll
  for (int k = 0; k < 16; ++k) {
    v2f o = O[k];
    O[k] = cc * o + vse * P[k];
    P[k] = cc * P[k] - vse * o;
  }
  const float d = t * apq;
  nO = fmaxf(isp ? nO - d : nO + d, 0.f);
  nP = fmaxf(isp ? nP + d : nP - d, 0.f);
}

__global__ __launch_bounds__(64, 2) void woodbury_sqrtm_blk(
    const float* __restrict__ invD2g, const float* __restrict__ Vg,
    float* __restrict__ out) {
  const int lane = threadIdx.x;
  const int q = lane >> 4;   // batch slot within the wave
  const int l = lane & 15;   // lane within the 16-lane batch group
  const int b = blockIdx.x * 4 + q;
  const int ca = 2 * l;      // own columns ca, ca+1

  // LDS: setup region and epilogue FT alias.
  __shared__ __align__(16) char lds[17408];
  float* adS = (float*)lds;              // [4][32]        @0     512
  float* Vs = (float*)(lds + 512);       // [4][32][8]     @512   4096
  double* Md = (double*)(lds + 4608);    // [4][8][9] f64  @4608  2304
  float* Uf = (float*)(lds + 6912);      // [4][32][8]     @6912  4096
  float* FT = (float*)lds;               // [4][32][34]    @0     17408 (epi)

  // ---- load inputs: invD2 pair + V rows ca, ca+1 ----
  const float2 adp = *(const float2*)(invD2g + (size_t)b * 32 + ca);
  const float ada = adp.x, adb = adp.y;
  adS[q * 32 + ca] = ada;
  adS[q * 32 + ca + 1] = adb;
  const float4 va0 = *(const float4*)(Vg + (size_t)b * 256 + ca * 8);
  const float4 va1 = *(const float4*)(Vg + (size_t)b * 256 + ca * 8 + 4);
  const float4 vb0 = *(const float4*)(Vg + (size_t)b * 256 + ca * 8 + 8);
  const float4 vb1 = *(const float4*)(Vg + (size_t)b * 256 + ca * 8 + 12);
  *(float4*)(Vs + (q * 32 + ca) * 8) = va0;
  *(float4*)(Vs + (q * 32 + ca) * 8 + 4) = va1;
  *(float4*)(Vs + (q * 32 + ca + 1) * 8) = vb0;
  *(float4*)(Vs + (q * 32 + ca + 1) * 8 + 4) = vb1;
  __syncthreads();

  // ---- M = I + V^T diag(invD2) V (8x8; lane: row r, 4 cols; f64 acc) ----
  {
    const int r = l >> 1, c0 = (l & 1) * 4;
    double m0 = 0, m1 = 0, m2 = 0, m3 = 0;
    const float* vq = Vs + q * 256;
    const float* aq = adS + q * 32;
    for (int y = 0; y < 32; ++y) {
      const double pr = (double)vq[y * 8 + r] * (double)aq[y];
      m0 += pr * (double)vq[y * 8 + c0 + 0];
      m1 += pr * (double)vq[y * 8 + c0 + 1];
      m2 += pr * (double)vq[y * 8 + c0 + 2];
      m3 += pr * (double)vq[y * 8 + c0 + 3];
    }
    double* Mq = Md + q * 72;
    Mq[r * 9 + c0 + 0] = m0 + ((r == c0 + 0) ? 1.0 : 0.0);
    Mq[r * 9 + c0 + 1] = m1 + ((r == c0 + 1) ? 1.0 : 0.0);
    Mq[r * 9 + c0 + 2] = m2 + ((r == c0 + 2) ? 1.0 : 0.0);
    Mq[r * 9 + c0 + 3] = m3 + ((r == c0 + 3) ? 1.0 : 0.0);
  }
  __syncthreads();

  // ---- Cholesky M = L L^T in place (lower), serial per batch (f64) ----
  if (l == 0) {
    double* M = Md + q * 72;
    for (int k = 0; k < 8; ++k) {
      double d = M[k * 9 + k];
      for (int i = 0; i < k; ++i) {
        const double lv = M[k * 9 + i];
        d -= lv * lv;
      }
      const double lkk = sqrt(fmax(d, 1e-30));
      M[k * 9 + k] = lkk;
      const double inv = 1.0 / lkk;
      for (int r = k + 1; r < 8; ++r) {
        double v = M[r * 9 + k];
        for (int i = 0; i < k; ++i) v -= M[r * 9 + i] * M[k * 9 + i];
        M[r * 9 + k] = v * inv;
      }
    }
  }
  __syncthreads();

  // ---- U rows ca, ca+1: solve U L^T = W (W row = V row * invD2) f64 ----
  float ua[8], ub[8];
  {
    const double* L = Md + q * 72;
    const float wa[8] = {va0.x * ada, va0.y * ada, va0.z * ada, va0.w * ada,
                         va1.x * ada, va1.y * ada, va1.z * ada, va1.w * ada};
    const float wb[8] = {vb0.x * adb, vb0.y * adb, vb0.z * adb, vb0.w * adb,
                         vb1.x * adb, vb1.y * adb, vb1.z * adb, vb1.w * adb};
    double ta[8], tb[8];
#pragma unroll
    for (int jj = 0; jj < 8; ++jj) {
      double sa = (double)wa[jj], sb = (double)wb[jj];
      for (int i = 0; i < jj; ++i) {
        const double lv = L[jj * 9 + i];
        sa -= ta[i] * lv;
        sb -= tb[i] * lv;
      }
      const double inv = 1.0 / L[jj * 9 + jj];
      ta[jj] = sa * inv;
      tb[jj] = sb * inv;
      ua[jj] = (float)ta[jj];
      ub[jj] = (float)tb[jj];
    }
    float* ur = Uf + q * 256;
#pragma unroll
    for (int k = 0; k < 8; ++k) {
      ur[ca * 8 + k] = ua[k];
      ur[(ca + 1) * 8 + k] = ub[k];
    }
  }
  __syncthreads();

  // ---- G columns ca, ca+1: G[i][j] = d_ij(invD2_i+eps) - (U U^T)_ij ----
  v2f gA[16], gB[16];
  {
    const float* uq = Uf + q * 256;
    for (int i = 0; i < 32; ++i) {
      const float* ui = uq + i * 8;
      float sa = 0.f, sb = 0.f;
#pragma unroll
      for (int k = 0; k < 8; ++k) {
        sa = fmaf(ui[k], ua[k], sa);
        sb = fmaf(ui[k], ub[k], sb);
      }
      float gva = -sa, gvb = -sb;
      if (i == ca) gva += ada + 1e-6f;
      if (i == ca + 1) gvb += adb + 1e-6f;
      if (i & 1) {
        gA[i >> 1].y = gva;
        gB[i >> 1].y = gvb;
      } else {
        gA[i >> 1].x = gva;
        gB[i >> 1].x = gvb;
      }
    }
  }
  __syncthreads();  // setup LDS dead; FT aliasing safe after this point

  // ---- block Jacobi: 7 sweeps x 15 meetings ----
  const int self4 = lane << 2;
  float nA = 0.f, nB = 0.f;
  for (int sweep = 0; sweep < 7; ++sweep) {
    nA = dotcols(gA, gA);  // fresh norms kill incremental drift
    nB = dotcols(gB, gB);
    for (int m = 1; m < 16; ++m) {
      // own-pair rotation BEFORE the exchange (both lanes do their own)
      crossrot(gA, nA, gB, nB, true);
      // pull partner block once; pin so it cannot be re-materialized
      const int pa4 = self4 ^ (m << 2);
      v2f pA[16], pB[16];
#pragma unroll
      for (int k = 0; k < 16; ++k) {
        v2f t0, t1;
        t0.x = bperm1(pa4, gA[k].x);
        t0.y = bperm1(pa4, gA[k].y);
        PIN2(t0);
        pA[k] = t0;
        t1.x = bperm1(pa4, gB[k].x);
        t1.y = bperm1(pa4, gB[k].y);
        PIN2(t1);
        pB[k] = t1;
      }
      float pnA = bperm1(pa4, nA);
      float pnB = bperm1(pa4, nB);
      const bool isp = l < (l ^ m);  // own columns are canonical-lower
      // 4 cross rotations; stage {1,2} then {3,4}: disjoint pairs commute
      crossrot(gA, nA, pA, pnA, isp);
      crossrot(gB, nB, pB, pnB, isp);
      crossrot(gA, nA, pB, pnB, isp);
      crossrot(gB, nB, pA, pnA, isp);
    }
  }

  // ---- epilogue: lam_k = ||g_k||; out = F F^T with f_k = g_k lam^-3/4 ----
  float b2a = fmaxf(dotcols(gA, gA), 1e-20f);
  float b2b = fmaxf(dotcols(gB, gB), 1e-20f);
  const float la = sqrtf(b2a), lb = sqrtf(b2b);
  const float swa = 1.f / sqrtf(la * sqrtf(la));  // la^-3/4
  const float swb = 1.f / sqrtf(lb * sqrtf(lb));

  float* FTq = FT + q * 1088;  // [32][34]
#pragma unroll
  for (int k = 0; k < 16; ++k) {
    float2 w0 = {gA[k].x * swa, gB[k].x * swb};  // row 2k, cols ca,ca+1
    float2 w1 = {gA[k].y * swa, gB[k].y * swb};  // row 2k+1
    *(float2*)(FTq + (2 * k) * 34 + ca) = w0;
    *(float2*)(FTq + (2 * k + 1) * 34 + ca) = w1;
  }
  __syncthreads();

  // own F-rows ca, ca+1 into registers
  float ra[32], rb[32];
  {
    const float4* rowa = (const float4*)(FTq + ca * 34);
    const float4* rowb = (const float4*)(FTq + (ca + 1) * 34);
#pragma unroll
    for (int c4 = 0; c4 < 8; ++c4) {
      const float4 x = rowa[c4], y = rowb[c4];
      ra[4 * c4 + 0] = x.x; ra[4 * c4 + 1] = x.y;
      ra[4 * c4 + 2] = x.z; ra[4 * c4 + 3] = x.w;
      rb[4 * c4 + 0] = y.x; rb[4 * c4 + 1] = y.y;
      rb[4 * c4 + 2] = y.z; rb[4 * c4 + 3] = y.w;
    }
  }
  float* ob = out + (size_t)b * 1024;
  for (int i = 0; i < 32; ++i) {
    const float4* ri = (const float4*)(FTq + i * 34);
    float sa = 0.f, sb = 0.f;
#pragma unroll
    for (int c4 = 0; c4 < 8; ++c4) {
      const float4 v = ri[c4];  // broadcast within the 16-lane group
      sa = fmaf(v.x, ra[4 * c4 + 0], sa);
      sa = fmaf(v.y, ra[4 * c4 + 1], sa);
      sa = fmaf(v.z, ra[4 * c4 + 2], sa);
      sa = fmaf(v.w, ra[4 * c4 + 3], sa);
      sb = fmaf(v.x, rb[4 * c4 + 0], sb);
      sb = fmaf(v.y, rb[4 * c4 + 1], sb);
      sb = fmaf(v.z, rb[4 * c4 + 2], sb);
      sb = fmaf(v.w, rb[4 * c4 + 3], sb);
    }
    *(float2*)(ob + i * 32 + ca) = make_float2(sa, sb);  // coalesced 128B/quarter
  }
}

// ---------------------------------------------------------------------------
extern "C" void kernel_launch(void* const* d_in, const int* in_sizes, int n_in,
                              void* d_out, int out_size, void* d_ws,
                              size_t ws_size, hipStream_t stream) {
  const float* x = (const float*)d_in[0];
  const float* W1 = (const float*)d_in[1];
  const float* b1 = (const float*)d_in[2];
  const float* WD = (const float*)d_in[3];
  const float* bD = (const float*)d_in[4];
  const float* WV = (const float*)d_in[5];
  const float* bV = (const float*)d_in[6];
  float* out = (float*)d_out;

  float* feat = out;                             // [16384,512] dead before out
  float* invD2 = (float*)d_ws;                   // [16384,32]
  float* V = (float*)d_ws + (size_t)16384 * 32;  // [16384,256]

  gemm_act<1><<<dim3(512 / 64, 16384 / 64), 256, 0, stream>>>(
      x, W1, b1, feat, 16384, 512, 128);
  gemm_act<2><<<dim3(1, 16384 / 64), 256, 0, stream>>>(
      feat, WD, bD, invD2, 16384, 32, 512);
  gemm_act<0><<<dim3(256 / 64, 16384 / 64), 256, 0, stream>>>(
      feat, WV, bV, V, 16384, 256, 512);
  woodbury_sqrtm_blk<<<16384 / 4, 64, 0, stream>>>(invD2, V, out);
}